// Round 14
// baseline (830.869 us; speedup 1.0000x reference)
//
#include <hip/hip_runtime.h>

// ---------------------------------------------------------------------------
// out[b,t,f] = sum_d x[b,t,d] * (W[d,f] / scale[f])
// GEMM: M=8192 (B*T), K=4096 (D), N=16384 (F)
// Round 14: full register double-buffering of MFMA fragments to break the
// LDS/MFMA serial-sum (R10-R13 all measured = serial sum of the two pipes).
// 256-thread blocks (4 waves, 2x2), 128x128 block tile, 64x64 wave tile,
// 3 blocks/CU (launch_bounds(256,3), ~160 VGPR), LDS 32KB/block. Per tile:
// one {lgkm0+vmcnt0+barrier} sync point, then 8 ds_reads (tile t+1) + 4 GLL
// (tile t+2) issued BEFORE the 16-MFMA cluster (tile t) that covers their
// drain. i8 16x16x64 MFMA, granule swizzle, XCD supertile.
// ws: [0,32M) xq int8 ; [32M,96M) WT int8 ; [96M,+32K) xs f32.
// ---------------------------------------------------------------------------

namespace {

constexpr int MD = 8192;    // B*T
constexpr int ND = 16384;   // F
constexpr int KD = 4096;    // D
constexpr int NT = KD / 64; // 64 k-tiles of BK=64

typedef float fl4 __attribute__((ext_vector_type(4)));
typedef unsigned int u32x4 __attribute__((ext_vector_type(4)));
typedef int i32x4 __attribute__((ext_vector_type(4)));

__device__ __forceinline__ unsigned int pack4(fl4 v, float sc) {
  int q0 = __float2int_rn(v.x * sc);
  int q1 = __float2int_rn(v.y * sc);
  int q2 = __float2int_rn(v.z * sc);
  int q3 = __float2int_rn(v.w * sc);
  return (q0 & 0xFF) | ((q1 & 0xFF) << 8) | ((q2 & 0xFF) << 16) |
         ((q3 & 0xFF) << 24);
}

// ---- x fp32 [M][K] -> int8 [M][K] + per-row scale -------------------------
__global__ __launch_bounds__(256) void quant_x_kernel(
    const float* __restrict__ x, signed char* __restrict__ xq,
    float* __restrict__ xs) {
  const int row = blockIdx.x;
  const int t   = threadIdx.x;
  const float* xr = x + (size_t)row * KD + t * 16;
  fl4 v0 = *(const fl4*)(xr);
  fl4 v1 = *(const fl4*)(xr + 4);
  fl4 v2 = *(const fl4*)(xr + 8);
  fl4 v3 = *(const fl4*)(xr + 12);
  float m = 0.f;
  m = fmaxf(m, fmaxf(fmaxf(fabsf(v0.x), fabsf(v0.y)), fmaxf(fabsf(v0.z), fabsf(v0.w))));
  m = fmaxf(m, fmaxf(fmaxf(fabsf(v1.x), fabsf(v1.y)), fmaxf(fabsf(v1.z), fabsf(v1.w))));
  m = fmaxf(m, fmaxf(fmaxf(fabsf(v2.x), fabsf(v2.y)), fmaxf(fabsf(v2.z), fabsf(v2.w))));
  m = fmaxf(m, fmaxf(fmaxf(fabsf(v3.x), fabsf(v3.y)), fmaxf(fabsf(v3.z), fabsf(v3.w))));
#pragma unroll
  for (int off = 32; off; off >>= 1) m = fmaxf(m, __shfl_xor(m, off));
  __shared__ float red[4];
  if ((t & 63) == 0) red[t >> 6] = m;
  __syncthreads();
  m = fmaxf(fmaxf(red[0], red[1]), fmaxf(red[2], red[3]));
  const float sc = (m > 0.f) ? 127.0f / m : 0.f;
  if (t == 0) xs[row] = (m > 0.f) ? m / 127.0f : 0.f;
  u32x4 o;
  o.x = pack4(v0, sc);
  o.y = pack4(v1, sc);
  o.z = pack4(v2, sc);
  o.w = pack4(v3, sc);
  *(u32x4*)(xq + (size_t)row * KD + t * 16) = o;
}

// ---- W int32 [K][N] -> int8 W^T [N][K] ------------------------------------
__global__ __launch_bounds__(256) void transpose_w_kernel(
    const int* __restrict__ W, signed char* __restrict__ WT) {
  constexpr int KC = 64;
  const int nb = blockIdx.x & 63;
  const int kb = blockIdx.x >> 6;
  const int n  = nb * 256 + threadIdx.x;
  const int k0 = kb * KC;
  const int* src = W + (size_t)k0 * ND + n;
  unsigned int buf[16];
#pragma unroll
  for (int i = 0; i < KC; i += 4) {
    unsigned int b0 = (unsigned)src[(size_t)(i + 0) * ND] & 0xFF;
    unsigned int b1 = (unsigned)src[(size_t)(i + 1) * ND] & 0xFF;
    unsigned int b2 = (unsigned)src[(size_t)(i + 2) * ND] & 0xFF;
    unsigned int b3 = (unsigned)src[(size_t)(i + 3) * ND] & 0xFF;
    buf[i >> 2] = b0 | (b1 << 8) | (b2 << 16) | (b3 << 24);
  }
  u32x4* dst = (u32x4*)(WT + (size_t)n * KD + k0);
#pragma unroll
  for (int j = 0; j < 4; ++j) {
    u32x4 o;
    o.x = buf[4 * j + 0];
    o.y = buf[4 * j + 1];
    o.z = buf[4 * j + 2];
    o.w = buf[4 * j + 3];
    dst[j] = o;
  }
}

// ---- 128x128 i8 GEMM, reg-dbuf fragments, 3 blocks/CU ---------------------

#define GLL16(g, l)                                                  \
  __builtin_amdgcn_global_load_lds(                                  \
      (const __attribute__((address_space(1))) void*)(g),            \
      (__attribute__((address_space(3))) void*)(l), 16, 0, 0)

#define BARRIER()    __builtin_amdgcn_s_barrier()
#define WAITL0()     asm volatile("s_waitcnt lgkmcnt(0)")
#define WAITV(N)     asm volatile("s_waitcnt vmcnt(" #N ")")
#define SCHED()      __builtin_amdgcn_sched_barrier(0)
#define PRIO1()      __builtin_amdgcn_s_setprio(1)
#define PRIO0()      __builtin_amdgcn_s_setprio(0)

__global__ __launch_bounds__(256, 3) void gemm_kernel(
    const signed char* __restrict__ Aq8,  // int8 [M][K]
    const signed char* __restrict__ Bq8,  // int8 [N][K] (W^T)
    const float* __restrict__ xs,         // [M] row scales
    const float* __restrict__ scale,      // [N]
    float* __restrict__ C) {              // f32 [M][N]
  // A tile 128x64 (8KB), B tile 128x64 (8KB), double-buffered: 32KB.
  __shared__ __align__(16) char Asm[2][8192];
  __shared__ __align__(16) char Bsm[2][8192];

  const int tid  = threadIdx.x;
  const int lane = tid & 63;
  const int w    = tid >> 6;   // wave 0..3
  const int wm   = w >> 1;     // 0..1 : A rows wm*64..+63
  const int wn   = w & 1;      // 0..1 : B cols wn*64..+63

  // XCD supertile: xcd owns tm band [8c,8c+8), sweeps tn tm-fastest.
  const int bid = blockIdx.x;            // 8192 = 8 chunks x 1024
  const int xcd = bid & 7;
  const int pos = bid >> 3;              // 0..1023
  const int tm  = (xcd << 3) | (pos & 7);   // 0..63
  const int tn  = pos >> 3;                 // 0..127
  const size_t brow = (size_t)tm * 128;
  const size_t bcol = (size_t)tn * 128;

  // staging: thread covers row tid>>2 (0..63) and row+64; granule pre-swz
  const int srow  = tid >> 2;
  const int sgran = (tid & 3) ^ ((tid >> 3) & 3);
  const signed char* Ag = Aq8 + (brow + srow) * (size_t)KD + sgran * 16;
  const signed char* Bg = Bq8 + (bcol + srow) * (size_t)KD + sgran * 16;

  // fragment reads: row = base + r15, swizzled k-granule
  const int r15  = lane & 15;
  const int kcsw = (((lane >> 4) ^ ((r15 >> 1) & 3)) << 4);
  const int aoff = (wm * 64 + r15) * 64 + kcsw;
  const int boff = (wn * 64 + r15) * 64 + kcsw;

  i32x4 acc[4][4];
#pragma unroll
  for (int i = 0; i < 4; ++i)
#pragma unroll
    for (int j = 0; j < 4; ++j) acc[i][j] = (i32x4){0, 0, 0, 0};

  // ---- prologue: tile0 -> buf0, tile1 -> buf1 (4 GLL each) ----
  GLL16(Ag,                        &Asm[0][0] + w * 1024);
  GLL16(Ag + (size_t)64 * KD,      &Asm[0][4096] + w * 1024);
  GLL16(Bg,                        &Bsm[0][0] + w * 1024);
  GLL16(Bg + (size_t)64 * KD,      &Bsm[0][4096] + w * 1024);
  GLL16(Ag + 64,                   &Asm[1][0] + w * 1024);
  GLL16(Ag + (size_t)64 * KD + 64, &Asm[1][4096] + w * 1024);
  GLL16(Bg + 64,                   &Bsm[1][0] + w * 1024);
  GLL16(Bg + (size_t)64 * KD + 64, &Bsm[1][4096] + w * 1024);
  SCHED();
  WAITV(4);   // tile0 resident; tile1's 4 loads in flight
  SCHED();
  BARRIER();
  SCHED();

  i32x4 a0[4], b0[4], a1[4], b1[4];
  // prime set0 from buf0 (tile 0)
#pragma unroll
  for (int mi = 0; mi < 4; ++mi)
    a0[mi] = *(const i32x4*)(&Asm[0][0] + aoff + mi * 1024);
#pragma unroll
  for (int ni = 0; ni < 4; ++ni)
    b0[ni] = *(const i32x4*)(&Bsm[0][0] + boff + ni * 1024);
  SCHED();

  // ---- main loop: 64 K-tiles, unrolled x2 with named reg sets ----
#define BODY(T, H, CA, CB, NA, NB)                                            \
  {                                                                           \
    const size_t kb2 = (size_t)(((T) + 2) & (NT - 1)) * 64;                   \
    WAITL0(); /* set C resident (issued last iter, covered by its MFMA) */    \
    SCHED();                                                                  \
    WAITV(0); /* GLL(T+1) resident in buf[H^1] (issued 1 iter ago) */         \
    SCHED();                                                                  \
    BARRIER(); /* buf[H^1] readable; buf[H] writable (reads drained) */       \
    SCHED();                                                                  \
    _Pragma("unroll") for (int mi = 0; mi < 4; ++mi)                          \
        NA[mi] = *(const i32x4*)(&Asm[(H) ^ 1][0] + aoff + mi * 1024);        \
    _Pragma("unroll") for (int ni = 0; ni < 4; ++ni)                          \
        NB[ni] = *(const i32x4*)(&Bsm[(H) ^ 1][0] + boff + ni * 1024);        \
    SCHED();                                                                  \
    GLL16(Ag + kb2,                   &Asm[H][0] + w * 1024);                 \
    GLL16(Ag + (size_t)64 * KD + kb2, &Asm[H][4096] + w * 1024);              \
    GLL16(Bg + kb2,                   &Bsm[H][0] + w * 1024);                 \
    GLL16(Bg + (size_t)64 * KD + kb2, &Bsm[H][4096] + w * 1024);              \
    SCHED();                                                                  \
    PRIO1();                                                                  \
    _Pragma("unroll") for (int mi = 0; mi < 4; ++mi)                          \
    _Pragma("unroll") for (int ni = 0; ni < 4; ++ni)                          \
        acc[mi][ni] = __builtin_amdgcn_mfma_i32_16x16x64_i8(                  \
            CA[mi], CB[ni], acc[mi][ni], 0, 0, 0);                            \
    PRIO0();                                                                  \
    SCHED();                                                                  \
  }

  for (int it = 0; it < NT; it += 2) {
    BODY(it,     0, a0, b0, a1, b1);
    BODY(it + 1, 1, a1, b1, a0, b0);
  }
#undef BODY

  // ---- epilogue: float(acc) * xs[row] * (1/scale[col]) -> C ----
  const int r4 = (lane >> 4) << 2;
  float sxv[4][4];
#pragma unroll
  for (int mi = 0; mi < 4; ++mi)
#pragma unroll
    for (int r = 0; r < 4; ++r)
      sxv[mi][r] = xs[brow + wm * 64 + mi * 16 + r4 + r];
#pragma unroll
  for (int ni = 0; ni < 4; ++ni) {
    const size_t col = bcol + wn * 64 + ni * 16 + r15;
    const float inv = 1.0f / scale[col];
#pragma unroll
    for (int mi = 0; mi < 4; ++mi) {
      float* cp = C + (brow + wm * 64 + mi * 16 + r4) * (size_t)ND + col;
#pragma unroll
      for (int r = 0; r < 4; ++r)
        cp[(size_t)r * ND] = (float)acc[mi][ni][r] * sxv[mi][r] * inv;
    }
  }
}

}  // namespace

extern "C" void kernel_launch(void* const* d_in, const int* in_sizes, int n_in,
                              void* d_out, int out_size, void* d_ws,
                              size_t ws_size, hipStream_t stream) {
  const float* x     = (const float*)d_in[0];
  const int*   W     = (const int*)d_in[1];
  const float* scale = (const float*)d_in[2];
  float*       out   = (float*)d_out;

  signed char* xq = (signed char*)d_ws;                                  // 32 MB
  signed char* wq = (signed char*)d_ws + (size_t)32 * 1024 * 1024;       // 64 MB
  float*       xs = (float*)((char*)d_ws + (size_t)96 * 1024 * 1024);    // 32 KB

  quant_x_kernel<<<8192, 256, 0, stream>>>(x, xq, xs);
  transpose_w_kernel<<<4096, 256, 0, stream>>>(W, wq);
  gemm_kernel<<<8192, 256, 0, stream>>>(xq, wq, xs, scale, out);
}

// Round 15
// 748.746 us; speedup vs baseline: 1.1097x; 1.1097x over previous
//
#include <hip/hip_runtime.h>

// ---------------------------------------------------------------------------
// out[b,t,f] = sum_d x[b,t,d] * (W[d,f] / scale[f])
// GEMM: M=8192 (B*T), K=4096 (D), N=16384 (F)
// Round 15: GEMM reverted byte-identical to R13 (best: 637us, MfmaUtil 39.4%
// = the i8-translated LDS-bandwidth ceiling of this structure family).
// Delta this round: transpose_w vectorized 2-wide along n (dwordx2 loads,
// half the load instructions, 2x per-thread MLP). Quant unchanged.
// ws: [0,32M) xq int8 ; [32M,96M) WT int8 ; [96M,+32K) xs f32.
// ---------------------------------------------------------------------------

namespace {

constexpr int MD = 8192;    // B*T
constexpr int ND = 16384;   // F
constexpr int KD = 4096;    // D
constexpr int NT = KD / 64; // 64 k-tiles of BK=64

typedef float fl4 __attribute__((ext_vector_type(4)));
typedef unsigned int u32x4 __attribute__((ext_vector_type(4)));
typedef int i32x4 __attribute__((ext_vector_type(4)));
typedef int i32x2 __attribute__((ext_vector_type(2)));

__device__ __forceinline__ unsigned int pack4(fl4 v, float sc) {
  int q0 = __float2int_rn(v.x * sc);
  int q1 = __float2int_rn(v.y * sc);
  int q2 = __float2int_rn(v.z * sc);
  int q3 = __float2int_rn(v.w * sc);
  return (q0 & 0xFF) | ((q1 & 0xFF) << 8) | ((q2 & 0xFF) << 16) |
         ((q3 & 0xFF) << 24);
}

// ---- x fp32 [M][K] -> int8 [M][K] + per-row scale -------------------------
__global__ __launch_bounds__(256) void quant_x_kernel(
    const float* __restrict__ x, signed char* __restrict__ xq,
    float* __restrict__ xs) {
  const int row = blockIdx.x;
  const int t   = threadIdx.x;
  const float* xr = x + (size_t)row * KD + t * 16;
  fl4 v0 = *(const fl4*)(xr);
  fl4 v1 = *(const fl4*)(xr + 4);
  fl4 v2 = *(const fl4*)(xr + 8);
  fl4 v3 = *(const fl4*)(xr + 12);
  float m = 0.f;
  m = fmaxf(m, fmaxf(fmaxf(fabsf(v0.x), fabsf(v0.y)), fmaxf(fabsf(v0.z), fabsf(v0.w))));
  m = fmaxf(m, fmaxf(fmaxf(fabsf(v1.x), fabsf(v1.y)), fmaxf(fabsf(v1.z), fabsf(v1.w))));
  m = fmaxf(m, fmaxf(fmaxf(fabsf(v2.x), fabsf(v2.y)), fmaxf(fabsf(v2.z), fabsf(v2.w))));
  m = fmaxf(m, fmaxf(fmaxf(fabsf(v3.x), fabsf(v3.y)), fmaxf(fabsf(v3.z), fabsf(v3.w))));
#pragma unroll
  for (int off = 32; off; off >>= 1) m = fmaxf(m, __shfl_xor(m, off));
  __shared__ float red[4];
  if ((t & 63) == 0) red[t >> 6] = m;
  __syncthreads();
  m = fmaxf(fmaxf(red[0], red[1]), fmaxf(red[2], red[3]));
  const float sc = (m > 0.f) ? 127.0f / m : 0.f;
  if (t == 0) xs[row] = (m > 0.f) ? m / 127.0f : 0.f;
  u32x4 o;
  o.x = pack4(v0, sc);
  o.y = pack4(v1, sc);
  o.z = pack4(v2, sc);
  o.w = pack4(v3, sc);
  *(u32x4*)(xq + (size_t)row * KD + t * 16) = o;
}

// ---- W int32 [K][N] -> int8 W^T [N][K], 2 columns per thread --------------
__global__ __launch_bounds__(256) void transpose_w_kernel(
    const int* __restrict__ W, signed char* __restrict__ WT) {
  constexpr int KC = 64;
  const int nb = blockIdx.x & 31;   // 32 n-blocks of 512 columns
  const int kb = blockIdx.x >> 5;   // 64 k-chunks
  const int n0 = nb * 512 + threadIdx.x * 2;
  const int k0 = kb * KC;
  const int* src = W + (size_t)k0 * ND + n0;

  unsigned int c0[KC / 4], c1[KC / 4];
#pragma unroll
  for (int j = 0; j < KC / 4; ++j) { c0[j] = 0u; c1[j] = 0u; }
#pragma unroll
  for (int i = 0; i < KC; ++i) {
    i32x2 v = *(const i32x2*)(src + (size_t)i * ND);
    c0[i >> 2] |= ((unsigned)v.x & 0xFF) << ((i & 3) * 8);
    c1[i >> 2] |= ((unsigned)v.y & 0xFF) << ((i & 3) * 8);
  }
  u32x4* d0 = (u32x4*)(WT + (size_t)(n0 + 0) * KD + k0);
  u32x4* d1 = (u32x4*)(WT + (size_t)(n0 + 1) * KD + k0);
#pragma unroll
  for (int j = 0; j < 4; ++j) {
    u32x4 o0, o1;
    o0.x = c0[4 * j + 0]; o0.y = c0[4 * j + 1];
    o0.z = c0[4 * j + 2]; o0.w = c0[4 * j + 3];
    o1.x = c1[4 * j + 0]; o1.y = c1[4 * j + 1];
    o1.z = c1[4 * j + 2]; o1.w = c1[4 * j + 3];
    d0[j] = o0;
    d1[j] = o1;
  }
}

// ---- 256x128 i8 GEMM, 2 blocks/CU, covered waits (R13, unchanged) ---------

#define GLL16(g, l)                                                  \
  __builtin_amdgcn_global_load_lds(                                  \
      (const __attribute__((address_space(1))) void*)(g),            \
      (__attribute__((address_space(3))) void*)(l), 16, 0, 0)

#define BARRIER()    __builtin_amdgcn_s_barrier()
#define WAITL(N)     asm volatile("s_waitcnt lgkmcnt(" #N ")")
#define WAITV(N)     asm volatile("s_waitcnt vmcnt(" #N ")")
#define SCHED()      __builtin_amdgcn_sched_barrier(0)
#define PRIO1()      __builtin_amdgcn_s_setprio(1)
#define PRIO0()      __builtin_amdgcn_s_setprio(0)

__global__ __launch_bounds__(512, 4) void gemm_kernel(
    const signed char* __restrict__ Aq8,  // int8 [M][K]
    const signed char* __restrict__ Bq8,  // int8 [N][K] (W^T)
    const float* __restrict__ xs,         // [M] row scales
    const float* __restrict__ scale,      // [N]
    float* __restrict__ C) {              // f32 [M][N]
  __shared__ __align__(16) char Asm[2][16384];
  __shared__ __align__(16) char Bsm[2][8192];

  const int tid  = threadIdx.x;
  const int lane = tid & 63;
  const int w    = tid >> 6;   // wave 0..7
  const int wm   = w >> 1;     // 0..3 : A rows wm*64..+63
  const int wn   = w & 1;      // 0..1 : B cols wn*64..+63

  const int bid = blockIdx.x;            // 4096 = 8 chunks x 512
  const int xcd = bid & 7;
  const int pos = bid >> 3;
  const int tm  = (xcd << 2) | (pos & 3);   // 0..31
  const int tn  = pos >> 2;                 // 0..127
  const size_t brow = (size_t)tm * 256;
  const size_t bcol = (size_t)tn * 128;

  const int srow  = tid >> 2;
  const int sgran = (tid & 3) ^ ((tid >> 3) & 3);
  const signed char* Ag = Aq8 + (brow + srow) * (size_t)KD + sgran * 16;
  const signed char* Bg = Bq8 + (bcol + srow) * (size_t)KD + sgran * 16;

  const int r15  = lane & 15;
  const int kcsw = (((lane >> 4) ^ ((r15 >> 1) & 3)) << 4);

  i32x4 acc[4][4];
#pragma unroll
  for (int i = 0; i < 4; ++i)
#pragma unroll
    for (int j = 0; j < 4; ++j) acc[i][j] = (i32x4){0, 0, 0, 0};

  // ---- prologue: tiles 0 (buf0) and 1 (buf1), 3 GLL each ----
  GLL16(Ag,                         &Asm[0][0] + w * 1024);
  GLL16(Ag + (size_t)128 * KD,      &Asm[0][8192] + w * 1024);
  GLL16(Bg,                         &Bsm[0][0] + w * 1024);
  GLL16(Ag + 64,                    &Asm[1][0] + w * 1024);
  GLL16(Ag + (size_t)128 * KD + 64, &Asm[1][8192] + w * 1024);
  GLL16(Bg + 64,                    &Bsm[1][0] + w * 1024);
  SCHED();
  WAITV(3);
  SCHED();
  BARRIER();
  SCHED();

  i32x4 a[4], b[4];
  {
    const char* Ab = &Asm[0][0] + (wm * 64 + r15) * 64 + kcsw;
    const char* Bb = &Bsm[0][0] + (wn * 64 + r15) * 64 + kcsw;
    a[2] = *(const i32x4*)(Ab + 2 * 1024);
    a[3] = *(const i32x4*)(Ab + 3 * 1024);
    SCHED();
    a[0] = *(const i32x4*)(Ab + 0 * 1024);
    a[1] = *(const i32x4*)(Ab + 1 * 1024);
    SCHED();
    b[0] = *(const i32x4*)(Bb + 0 * 1024);
    b[1] = *(const i32x4*)(Bb + 1 * 1024);
  }
  SCHED();

  // ---- main loop: 64 K-tiles, 1 barrier each ----
#pragma unroll 2
  for (int it = 0; it < NT; ++it) {
    const int h = it & 1;
    const char* Bb  = &Bsm[h][0] + (wn * 64 + r15) * 64 + kcsw;
    const char* AbN = &Asm[h ^ 1][0] + (wm * 64 + r15) * 64 + kcsw;
    const char* BbN = &Bsm[h ^ 1][0] + (wn * 64 + r15) * 64 + kcsw;
    const size_t kb2 = (size_t)((it + 2) & (NT - 1)) * 64;

    b[2] = *(const i32x4*)(Bb + 2 * 1024);
    b[3] = *(const i32x4*)(Bb + 3 * 1024);
    SCHED();
    WAITL(2);
    SCHED();
    PRIO1();
#pragma unroll
    for (int mi = 0; mi < 4; ++mi)
#pragma unroll
      for (int ni = 0; ni < 2; ++ni)
        acc[mi][ni] = __builtin_amdgcn_mfma_i32_16x16x64_i8(
            a[mi], b[ni], acc[mi][ni], 0, 0, 0);
    PRIO0();
    SCHED();
    WAITL(0);
    SCHED();
    PRIO1();
#pragma unroll
    for (int mi = 2; mi < 4; ++mi)
#pragma unroll
      for (int ni = 2; ni < 4; ++ni)
        acc[mi][ni] = __builtin_amdgcn_mfma_i32_16x16x64_i8(
            a[mi], b[ni], acc[mi][ni], 0, 0, 0);
    PRIO0();
    SCHED();
    WAITV(0);
    SCHED();
    BARRIER();
    SCHED();
    a[2] = *(const i32x4*)(AbN + 2 * 1024);
    a[3] = *(const i32x4*)(AbN + 3 * 1024);
    SCHED();
    PRIO1();
#pragma unroll
    for (int mi = 0; mi < 2; ++mi)
#pragma unroll
      for (int ni = 2; ni < 4; ++ni)
        acc[mi][ni] = __builtin_amdgcn_mfma_i32_16x16x64_i8(
            a[mi], b[ni], acc[mi][ni], 0, 0, 0);
    PRIO0();
    SCHED();
    a[0] = *(const i32x4*)(AbN + 0 * 1024);
    a[1] = *(const i32x4*)(AbN + 1 * 1024);
    SCHED();
    b[0] = *(const i32x4*)(BbN + 0 * 1024);
    b[1] = *(const i32x4*)(BbN + 1 * 1024);
    SCHED();
    GLL16(Ag + kb2,                    &Asm[h][0] + w * 1024);
    GLL16(Ag + (size_t)128 * KD + kb2, &Asm[h][8192] + w * 1024);
    GLL16(Bg + kb2,                    &Bsm[h][0] + w * 1024);
    SCHED();
  }

  // ---- epilogue: float(acc) * xs[row] * (1/scale[col]) -> C ----
  const int r4 = (lane >> 4) << 2;
  float sxv[4][4];
#pragma unroll
  for (int mi = 0; mi < 4; ++mi)
#pragma unroll
    for (int r = 0; r < 4; ++r)
      sxv[mi][r] = xs[brow + wm * 64 + mi * 16 + r4 + r];
#pragma unroll
  for (int ni = 0; ni < 4; ++ni) {
    const size_t col = bcol + wn * 64 + ni * 16 + r15;
    const float inv = 1.0f / scale[col];
#pragma unroll
    for (int mi = 0; mi < 4; ++mi) {
      float* cp = C + (brow + wm * 64 + mi * 16 + r4) * (size_t)ND + col;
#pragma unroll
      for (int r = 0; r < 4; ++r)
        cp[(size_t)r * ND] = (float)acc[mi][ni][r] * sxv[mi][r] * inv;
    }
  }
}

}  // namespace

extern "C" void kernel_launch(void* const* d_in, const int* in_sizes, int n_in,
                              void* d_out, int out_size, void* d_ws,
                              size_t ws_size, hipStream_t stream) {
  const float* x     = (const float*)d_in[0];
  const int*   W     = (const int*)d_in[1];
  const float* scale = (const float*)d_in[2];
  float*       out   = (float*)d_out;

  signed char* xq = (signed char*)d_ws;                                  // 32 MB
  signed char* wq = (signed char*)d_ws + (size_t)32 * 1024 * 1024;       // 64 MB
  float*       xs = (float*)((char*)d_ws + (size_t)96 * 1024 * 1024);    // 32 KB

  quant_x_kernel<<<8192, 256, 0, stream>>>(x, xq, xs);
  transpose_w_kernel<<<2048, 256, 0, stream>>>(W, wq);
  gemm_kernel<<<4096, 512, 0, stream>>>(xq, wq, xs, scale, out);
}